// Round 7
// baseline (450.595 us; speedup 1.0000x reference)
//
#include <hip/hip_runtime.h>
#include <hip/hip_bf16.h>
#include <stdint.h>

#define N 8192
#define D 128
#define NCHUNK 16
#define CHUNK (N / NCHUNK)      // 512 cols per chunk
#define RT 128                  // rows per block (4 waves x 32)
#define CT 64                   // cols per logical tile
#define NTILES (CHUNK / CT)     // 8

typedef short bf16x8 __attribute__((ext_vector_type(8)));
typedef float f32x4 __attribute__((ext_vector_type(4)));
typedef unsigned int uint32;
typedef unsigned long long uint64;

// ---- workspace layout (bytes) ----
#define OFF_ACC   0u                          // [0] float S_sum, [4] uint32 P_count
#define OFF_SQ2   1024u                       // 8192 floats
#define OFF_RPOS  (OFF_SQ2 + N * 4u)          // N uint32 per-row positive counts
#define OFF_M     (OFF_RPOS + N * 4u)         // NCHUNK*N floats (per-chunk row max)
#define OFF_L     (OFF_M + NCHUNK * N * 4u)
#define OFF_S     (OFF_L + NCHUNK * N * 4u)
#define OFF_F1    (OFF_S + NCHUNK * N * 4u)   // feat1 bf16
#define OFF_F2    (OFF_F1 + N * D * 2u)       // feat2 bf16
#define OFF_PACK  (OFF_F2 + N * D * 2u)       // N*N/8 bytes = 8 MB packed simi

// Convert feats to bf16; compute sq2[j] = ||feat2_j||^2.
__global__ __launch_bounds__(256)
void prep_kernel(const float* __restrict__ f1, const float* __restrict__ f2,
                 unsigned short* __restrict__ f1b, unsigned short* __restrict__ f2b,
                 float* __restrict__ sq2) {
    const int w    = blockIdx.x * 4 + (threadIdx.x >> 6);  // 0..1023
    const int lane = threadIdx.x & 63;
    for (int row = w; row < N; row += 1024) {
        float a0 = f1[row * D + lane];
        float a1 = f1[row * D + 64 + lane];
        float b0 = f2[row * D + lane];
        float b1 = f2[row * D + 64 + lane];
        __hip_bfloat16 t;
        t = __float2bfloat16(a0); f1b[row * D + lane]      = *(unsigned short*)&t;
        t = __float2bfloat16(a1); f1b[row * D + 64 + lane] = *(unsigned short*)&t;
        t = __float2bfloat16(b0); f2b[row * D + lane]      = *(unsigned short*)&t;
        t = __float2bfloat16(b1); f2b[row * D + 64 + lane] = *(unsigned short*)&t;
        float ss = b0 * b0 + b1 * b1;
        #pragma unroll
        for (int off = 32; off > 0; off >>= 1) ss += __shfl_xor(ss, off);
        if (lane == 0) sq2[row] = ss;
    }
}

// Streaming pack: simi (int32 {+1,-1}) -> 1 bit/entry (set iff ==1), natural
// order; per-row positive count (plain store, no atomics). One row per wave.
// Manual double-buffer: 16 loads (4 KB) for group g+1 in flight while group g
// is balloted -> up to 8 KB outstanding/wave.
__global__ __launch_bounds__(256)
void pack_kernel(const int* __restrict__ simi, uint64* __restrict__ packed,
                 uint32* __restrict__ rowpos) {
    const int wave = threadIdx.x >> 6;
    const int lane = threadIdx.x & 63;
    const int row  = blockIdx.x * 4 + wave;   // 0..N-1
    const int* rp = simi + (size_t)row * N;
    uint64* dstrow = packed + (size_t)row * (N / 64);
    uint32 pos = 0;
    int v[16];
    #pragma unroll
    for (int i = 0; i < 16; i++) v[i] = rp[i * 64 + lane];
    #pragma unroll
    for (int g = 0; g < 8; g++) {          // 8 groups x 1024 cols
        int w[16];
        if (g < 7) {
            #pragma unroll
            for (int i = 0; i < 16; i++) w[i] = rp[(g + 1) * 1024 + i * 64 + lane];
        }
        uint64 b[16];
        #pragma unroll
        for (int i = 0; i < 16; i++) b[i] = __ballot(v[i] == 1);  // bit k <-> col g*1024+i*64+k
        if (lane == 0) {
            #pragma unroll
            for (int i = 0; i < 8; i++) {
                ulonglong2 p = {b[2 * i], b[2 * i + 1]};
                *reinterpret_cast<ulonglong2*>(dstrow + g * 16 + 2 * i) = p;
            }
            #pragma unroll
            for (int i = 0; i < 16; i++) pos += (uint32)__popcll(b[i]);
        }
        if (g < 7) {
            #pragma unroll
            for (int i = 0; i < 16; i++) v[i] = w[i];
        }
    }
    if (lane == 0) rowpos[row] = pos;
}

// Fused GEMM + online softmax + masked accumulation. Barrier-free K-loop:
// no LDS — B fragments read per-MFMA straight from L2-resident f2b.
// Softmax safety (round 6 NaN post-mortem): fixed shift underflowed whole
// rows (row-max logits sit at -40..-60, data-dependent). Robust fix with no
// per-tile shuffle chains: PER-LANE online max over the lane's own columns,
// per-lane rescale; single cross-lane max/rescale/sum reduction at the end.
// Column permutation: acc[cf] lane lo holds global col cbase+4*lo+cf, whose
// mask bits are contiguous in one packed u32 at shift 4*(lo&7). Softmax sums
// are permutation-invariant.
__global__ __launch_bounds__(256)
void main_kernel(const unsigned short* __restrict__ f1b,
                 const unsigned short* __restrict__ f2b,
                 const float* __restrict__ sq2,
                 const uint32* __restrict__ packed32,
                 float* __restrict__ pm, float* __restrict__ pl, float* __restrict__ ps) {
    const int tid  = threadIdx.x;
    const int wave = tid >> 6;
    const int lane = tid & 63;
    const int lo   = lane & 15;
    const int hi   = lane >> 4;

    const int rowtile = blockIdx.x;       // 0..63
    const int chunk   = blockIdx.y;       // 0..15
    const int rbase   = rowtile * RT + wave * 32;
    const int cbase0  = chunk * CHUNK;

    // A fragments: 2 sets of 16 rows, full K=128, resident for the sweep.
    bf16x8 afrag[2][4];
    #pragma unroll
    for (int a = 0; a < 2; a++) {
        const unsigned short* ap = f1b + (size_t)(rbase + a * 16 + lo) * D + hi * 8;
        #pragma unroll
        for (int kk = 0; kk < 4; kk++)
            afrag[a][kk] = *reinterpret_cast<const bf16x8*>(ap + kk * 32);
    }

    // packed mask pointer: row rbase+hi*4(+a*16+r), word (cbase>>5)+(lo>>3)
    const uint32* pk = packed32 + (size_t)(rbase + hi * 4) * (N / 32)
                                + (cbase0 >> 5) + (lo >> 3);
    const int mshift = 4 * (lo & 7);

    // B fragment base: col cbase0 + 4*lo (+cf), k-offset hi*8 (+kk*32)
    const unsigned short* bp = f2b + (size_t)(cbase0 + 4 * lo) * D + hi * 8;

    // per-lane online-softmax state over this lane's own columns
    float m[2][4], l[2][4], s[2][4];
    #pragma unroll
    for (int a = 0; a < 2; a++)
        #pragma unroll
        for (int r = 0; r < 4; r++) { m[a][r] = -1e30f; l[a][r] = 0.f; s[a][r] = 0.f; }

    for (int t = 0; t < NTILES; t++) {
        // mask bits: one u32 per row (4 bits used), L2/L3-resident
        uint32 mb[2][4];
        #pragma unroll
        for (int a = 0; a < 2; a++)
            #pragma unroll
            for (int r = 0; r < 4; r++)
                mb[a][r] = (pk[(size_t)(a * 16 + r) * (N / 32)] >> mshift) & 0xfu;

        // MFMA: 32 rows x 64 cols; B fragments straight from global (L2)
        f32x4 acc[2][4];
        #pragma unroll
        for (int cf = 0; cf < 4; cf++) {
            acc[0][cf] = (f32x4){0.f, 0.f, 0.f, 0.f};
            acc[1][cf] = (f32x4){0.f, 0.f, 0.f, 0.f};
            const unsigned short* bc = bp + (size_t)(t * CT + cf) * D;
            #pragma unroll
            for (int kk = 0; kk < 4; kk++) {
                bf16x8 b = *reinterpret_cast<const bf16x8*>(bc + kk * 32);
                acc[0][cf] = __builtin_amdgcn_mfma_f32_16x16x32_bf16(afrag[0][kk], b, acc[0][cf], 0, 0, 0);
                acc[1][cf] = __builtin_amdgcn_mfma_f32_16x16x32_bf16(afrag[1][kk], b, acc[1][cf], 0, 0, 0);
            }
        }

        // logits lg = 2c - sq2[col] (row-constant sq1 dropped); per-lane
        // online max + rescale + accumulate — no cross-lane ops in the loop
        f32x4 sqv = *reinterpret_cast<const f32x4*>(sq2 + cbase0 + t * CT + 4 * lo);
        #pragma unroll
        for (int a = 0; a < 2; a++)
            #pragma unroll
            for (int r = 0; r < 4; r++) {
                float lg[4];
                #pragma unroll
                for (int cf = 0; cf < 4; cf++)
                    lg[cf] = 2.0f * acc[a][cf][r] - sqv[cf];
                float tm = fmaxf(fmaxf(lg[0], lg[1]), fmaxf(lg[2], lg[3]));
                float mn = fmaxf(m[a][r], tm);
                float al = __expf(m[a][r] - mn);
                m[a][r] = mn;
                float p[4];
                #pragma unroll
                for (int cf = 0; cf < 4; cf++) p[cf] = __expf(lg[cf] - mn);
                l[a][r] = l[a][r] * al + ((p[0] + p[1]) + (p[2] + p[3]));
                float sm = 0.f;
                #pragma unroll
                for (int cf = 0; cf < 4; cf++)
                    sm += ((mb[a][r] >> cf) & 1u) ? p[cf] : 0.f;
                s[a][r] = s[a][r] * al + sm;
            }
        pk += 2;  // 64 cols = 2 u32 words
    }

    // end: cross-lane (lo group, 16 lanes) max + rescale + sum, once
    #pragma unroll
    for (int a = 0; a < 2; a++)
        #pragma unroll
        for (int r = 0; r < 4; r++) {
            float M = m[a][r];
            #pragma unroll
            for (int off = 1; off < 16; off <<= 1)
                M = fmaxf(M, __shfl_xor(M, off));
            float sc = __expf(m[a][r] - M);
            float L = l[a][r] * sc, S = s[a][r] * sc;
            #pragma unroll
            for (int off = 1; off < 16; off <<= 1) {
                L += __shfl_xor(L, off);
                S += __shfl_xor(S, off);
            }
            if (lo == 0) {
                int row = rbase + a * 16 + hi * 4 + r;
                int idx = chunk * N + row;
                pm[idx] = M; pl[idx] = L; ps[idx] = S;
            }
        }
}

// Merge per-chunk (m,l,s) partials per row; accumulate sum of s/l and the
// positive count. 64 atomics total.
__global__ void merge_kernel(const float* __restrict__ pm, const float* __restrict__ pl,
                             const float* __restrict__ ps, const uint32* __restrict__ rowpos,
                             float* __restrict__ s_acc, uint32* __restrict__ pos_acc) {
    const int row = blockIdx.x * 256 + threadIdx.x;
    float M = -1e30f;
    #pragma unroll
    for (int k = 0; k < NCHUNK; k++) M = fmaxf(M, pm[k * N + row]);
    float L = 0.f, S = 0.f;
    #pragma unroll
    for (int k = 0; k < NCHUNK; k++) {
        float e = __expf(pm[k * N + row] - M);
        L += pl[k * N + row] * e;
        S += ps[k * N + row] * e;
    }
    float r = S / L;
    uint32 pc = rowpos[row];
    #pragma unroll
    for (int off = 32; off > 0; off >>= 1) {
        r  += __shfl_xor(r, off);
        pc += __shfl_xor(pc, off);
    }
    __shared__ float red[4];
    __shared__ uint32 redp[4];
    int lane = threadIdx.x & 63, w = threadIdx.x >> 6;
    if (lane == 0) { red[w] = r; redp[w] = pc; }
    __syncthreads();
    if (threadIdx.x == 0) {
        atomicAdd(s_acc, red[0] + red[1] + red[2] + red[3]);
        atomicAdd(pos_acc, redp[0] + redp[1] + redp[2] + redp[3]);
    }
}

__global__ void final_kernel(const float* __restrict__ s_acc, const uint32* __restrict__ pos_acc,
                             float* __restrict__ out) {
    double S = (double)s_acc[0];
    double C = (double)N * (double)N - (double)pos_acc[0];  // count(simi != 1)
    double n = (double)N;
    out[0] = (float)((2.0 * S + C - n) / (n * n));
}

extern "C" void kernel_launch(void* const* d_in, const int* in_sizes, int n_in,
                              void* d_out, int out_size, void* d_ws, size_t ws_size,
                              hipStream_t stream) {
    const float* f1   = (const float*)d_in[0];
    const float* f2   = (const float*)d_in[1];
    const int*   simi = (const int*)d_in[2];
    float* out = (float*)d_out;
    char* ws = (char*)d_ws;

    float*  acc_s  = (float*)(ws + OFF_ACC);
    uint32* acc_p  = (uint32*)(ws + OFF_ACC + 4);
    float*  sq2    = (float*)(ws + OFF_SQ2);
    uint32* rowpos = (uint32*)(ws + OFF_RPOS);
    float*  pm     = (float*)(ws + OFF_M);
    float*  pl     = (float*)(ws + OFF_L);
    float*  ps     = (float*)(ws + OFF_S);
    unsigned short* f1b = (unsigned short*)(ws + OFF_F1);
    unsigned short* f2b = (unsigned short*)(ws + OFF_F2);
    uint64* packed = (uint64*)(ws + OFF_PACK);

    hipMemsetAsync(ws + OFF_ACC, 0, 64, stream);
    prep_kernel<<<256, 256, 0, stream>>>(f1, f2, f1b, f2b, sq2);
    pack_kernel<<<N / 4, 256, 0, stream>>>(simi, packed, rowpos);
    main_kernel<<<dim3(N / RT, NCHUNK), 256, 0, stream>>>(f1b, f2b, sq2,
                                                          (const uint32*)packed, pm, pl, ps);
    merge_kernel<<<N / 256, 256, 0, stream>>>(pm, pl, ps, rowpos, acc_s, acc_p);
    final_kernel<<<1, 1, 0, stream>>>(acc_s, acc_p, out);
}

// Round 8
// 420.754 us; speedup vs baseline: 1.0709x; 1.0709x over previous
//
#include <hip/hip_runtime.h>
#include <hip/hip_bf16.h>
#include <stdint.h>

#define N 8192
#define D 128
#define NCHUNK 16
#define CHUNK (N / NCHUNK)      // 512 cols per chunk
#define RT 128                  // rows per block (4 waves x 32)
#define CT 64                   // cols per LDS tile
#define NTILES (CHUNK / CT)     // 8

typedef short bf16x8 __attribute__((ext_vector_type(8)));
typedef float f32x4 __attribute__((ext_vector_type(4)));
typedef unsigned int uint32;
typedef unsigned long long uint64;

// ---- workspace layout (bytes) ----
#define OFF_ACC   0u                          // [0] float S_sum, [4] uint32 P_count
#define OFF_SQ2   1024u                       // 8192 floats
#define OFF_RPOS  (OFF_SQ2 + N * 4u)          // N uint32 per-row positive counts
#define OFF_M     (OFF_RPOS + N * 4u)         // NCHUNK*N floats (per-chunk row max)
#define OFF_L     (OFF_M + NCHUNK * N * 4u)
#define OFF_S     (OFF_L + NCHUNK * N * 4u)
#define OFF_F1    (OFF_S + NCHUNK * N * 4u)   // feat1 bf16
#define OFF_F2    (OFF_F1 + N * D * 2u)       // feat2 bf16
#define OFF_PACK  (OFF_F2 + N * D * 2u)       // N*N/8 bytes = 8 MB packed simi

// Convert feats to bf16; compute sq2[j] = ||feat2_j||^2.
__global__ __launch_bounds__(256)
void prep_kernel(const float* __restrict__ f1, const float* __restrict__ f2,
                 unsigned short* __restrict__ f1b, unsigned short* __restrict__ f2b,
                 float* __restrict__ sq2) {
    const int w    = blockIdx.x * 4 + (threadIdx.x >> 6);  // 0..1023
    const int lane = threadIdx.x & 63;
    for (int row = w; row < N; row += 1024) {
        float a0 = f1[row * D + lane];
        float a1 = f1[row * D + 64 + lane];
        float b0 = f2[row * D + lane];
        float b1 = f2[row * D + 64 + lane];
        __hip_bfloat16 t;
        t = __float2bfloat16(a0); f1b[row * D + lane]      = *(unsigned short*)&t;
        t = __float2bfloat16(a1); f1b[row * D + 64 + lane] = *(unsigned short*)&t;
        t = __float2bfloat16(b0); f2b[row * D + lane]      = *(unsigned short*)&t;
        t = __float2bfloat16(b1); f2b[row * D + 64 + lane] = *(unsigned short*)&t;
        float ss = b0 * b0 + b1 * b1;
        #pragma unroll
        for (int off = 32; off > 0; off >>= 1) ss += __shfl_xor(ss, off);
        if (lane == 0) sq2[row] = ss;
    }
}

// Streaming pack: simi (int32 {+1,-1}) -> 1 bit/entry (set iff ==1), natural
// order; per-row positive count (plain store, no atomics). One row per wave.
// Manual double-buffer: 16 loads (4 KB) for group g+1 in flight while group g
// is balloted. (Unchanged from round 7 — this round isolates its cost.)
__global__ __launch_bounds__(256)
void pack_kernel(const int* __restrict__ simi, uint64* __restrict__ packed,
                 uint32* __restrict__ rowpos) {
    const int wave = threadIdx.x >> 6;
    const int lane = threadIdx.x & 63;
    const int row  = blockIdx.x * 4 + wave;   // 0..N-1
    const int* rp = simi + (size_t)row * N;
    uint64* dstrow = packed + (size_t)row * (N / 64);
    uint32 pos = 0;
    int v[16];
    #pragma unroll
    for (int i = 0; i < 16; i++) v[i] = rp[i * 64 + lane];
    #pragma unroll
    for (int g = 0; g < 8; g++) {          // 8 groups x 1024 cols
        int w[16];
        if (g < 7) {
            #pragma unroll
            for (int i = 0; i < 16; i++) w[i] = rp[(g + 1) * 1024 + i * 64 + lane];
        }
        uint64 b[16];
        #pragma unroll
        for (int i = 0; i < 16; i++) b[i] = __ballot(v[i] == 1);  // bit k <-> col g*1024+i*64+k
        if (lane == 0) {
            #pragma unroll
            for (int i = 0; i < 8; i++) {
                ulonglong2 p = {b[2 * i], b[2 * i + 1]};
                *reinterpret_cast<ulonglong2*>(dstrow + g * 16 + 2 * i) = p;
            }
            #pragma unroll
            for (int i = 0; i < 16; i++) pos += (uint32)__popcll(b[i]);
        }
        if (g < 7) {
            #pragma unroll
            for (int i = 0; i < 16; i++) v[i] = w[i];
        }
    }
    if (lane == 0) rowpos[row] = pos;
}

// Fused GEMM + online softmax + masked accumulation.
// R8 = R5's proven LDS-staged structure (66 us) + R7's per-lane online
// softmax (no cross-lane ops inside the K-loop; single reduction at end).
// Round 7's barrier-free global-B variant is reverted pending the pack/main
// cost split this round measures.
// Column permutation: LDS B-position q holds global col c(q)=4*(q&15)+(q>>4),
// so acc[cf] lane lo holds global col cbase+4*lo+cf -> its 4 mask bits are
// contiguous in one packed u32 at shift 4*(lo&7). Softmax sums are
// permutation-invariant.
__global__ __launch_bounds__(256)
void main_kernel(const unsigned short* __restrict__ f1b,
                 const unsigned short* __restrict__ f2b,
                 const float* __restrict__ sq2,
                 const uint32* __restrict__ packed32,
                 float* __restrict__ pm, float* __restrict__ pl, float* __restrict__ ps) {
    __shared__ unsigned short ldsB[CT * D];  // 16 KB, XOR-swizzled
    __shared__ float ldsSq[CHUNK];           // 2 KB, natural order

    const int tid  = threadIdx.x;
    const int wave = tid >> 6;
    const int lane = tid & 63;
    const int lo   = lane & 15;
    const int hi   = lane >> 4;

    const int rowtile = blockIdx.x;       // 0..63
    const int chunk   = blockIdx.y;       // 0..15
    const int rbase   = rowtile * RT + wave * 32;
    const int cbase0  = chunk * CHUNK;

    // stage sq2 for this chunk (covered by the first tile's barrier)
    for (int i = tid; i < CHUNK; i += 256) ldsSq[i] = sq2[cbase0 + i];

    // A fragments: 2 sets of 16 rows, full K=128, resident for the sweep.
    bf16x8 afrag[2][4];
    #pragma unroll
    for (int a = 0; a < 2; a++) {
        const unsigned short* ap = f1b + (size_t)(rbase + a * 16 + lo) * D + hi * 8;
        #pragma unroll
        for (int kk = 0; kk < 4; kk++)
            afrag[a][kk] = *reinterpret_cast<const bf16x8*>(ap + kk * 32);
    }

    const int sq_ = (tid >> 4);           // staging: position within 16-group
    const int sg_ = tid & 15;             // staging: 16B chunk index

    // packed mask pointer: row rbase+hi*4(+a*16+r), word (cbase>>5)+(lo>>3)
    const uint32* pk = packed32 + (size_t)(rbase + hi * 4) * (N / 32)
                                + (cbase0 >> 5) + (lo >> 3);
    const int mshift = 4 * (lo & 7);

    // per-lane online-softmax state over this lane's own columns
    float m[2][4], l[2][4], s[2][4];
    #pragma unroll
    for (int a = 0; a < 2; a++)
        #pragma unroll
        for (int r = 0; r < 4; r++) { m[a][r] = -1e30f; l[a][r] = 0.f; s[a][r] = 0.f; }

    for (int t = 0; t < NTILES; t++) {
        const int cbase = cbase0 + t * CT;

        // mask bits (before barrier -> overlap with staging loads)
        uint32 mb[2][4];
        #pragma unroll
        for (int a = 0; a < 2; a++)
            #pragma unroll
            for (int r = 0; r < 4; r++)
                mb[a][r] = (pk[(size_t)(a * 16 + r) * (N / 32)] >> mshift) & 0xfu;

        __syncthreads();  // previous tile's LDS reads complete
        // stage B tile: position q holds global col c(q)=4*(q&15)+(q>>4)
        #pragma unroll
        for (int it = 0; it < 4; it++) {
            int q = it * 16 + sq_;
            int c = 4 * (q & 15) + (q >> 4);
            const uint4 v = *reinterpret_cast<const uint4*>(f2b + (size_t)(cbase + c) * D + sg_ * 8);
            *reinterpret_cast<uint4*>(ldsB + q * D + ((sg_ ^ (q & 15)) * 8)) = v;
        }
        __syncthreads();

        // MFMA: 32 rows x 64 cols; each B fragment feeds both A sets
        f32x4 acc[2][4];
        #pragma unroll
        for (int cf = 0; cf < 4; cf++) {
            acc[0][cf] = (f32x4){0.f, 0.f, 0.f, 0.f};
            acc[1][cf] = (f32x4){0.f, 0.f, 0.f, 0.f};
            const int brow = cf * 16 + lo;
            #pragma unroll
            for (int kk = 0; kk < 4; kk++) {
                int g = kk * 4 + hi;
                bf16x8 b = *reinterpret_cast<const bf16x8*>(
                    ldsB + brow * D + ((g ^ (brow & 15)) * 8));
                acc[0][cf] = __builtin_amdgcn_mfma_f32_16x16x32_bf16(afrag[0][kk], b, acc[0][cf], 0, 0, 0);
                acc[1][cf] = __builtin_amdgcn_mfma_f32_16x16x32_bf16(afrag[1][kk], b, acc[1][cf], 0, 0, 0);
            }
        }

        // logits lg = 2c - sq2[col] (row-constant sq1 dropped); per-lane
        // online max + rescale + accumulate — no cross-lane ops in the loop
        f32x4 sqv = *reinterpret_cast<const f32x4*>(&ldsSq[t * CT + 4 * lo]);
        #pragma unroll
        for (int a = 0; a < 2; a++)
            #pragma unroll
            for (int r = 0; r < 4; r++) {
                float lg[4];
                #pragma unroll
                for (int cf = 0; cf < 4; cf++)
                    lg[cf] = 2.0f * acc[a][cf][r] - sqv[cf];
                float tm = fmaxf(fmaxf(lg[0], lg[1]), fmaxf(lg[2], lg[3]));
                float mn = fmaxf(m[a][r], tm);
                float al = __expf(m[a][r] - mn);
                m[a][r] = mn;
                float p[4];
                #pragma unroll
                for (int cf = 0; cf < 4; cf++) p[cf] = __expf(lg[cf] - mn);
                l[a][r] = l[a][r] * al + ((p[0] + p[1]) + (p[2] + p[3]));
                float sm = 0.f;
                #pragma unroll
                for (int cf = 0; cf < 4; cf++)
                    sm += ((mb[a][r] >> cf) & 1u) ? p[cf] : 0.f;
                s[a][r] = s[a][r] * al + sm;
            }
        pk += 2;  // 64 cols = 2 u32 words
    }

    // end: cross-lane (lo group, 16 lanes) max + rescale + sum, once
    #pragma unroll
    for (int a = 0; a < 2; a++)
        #pragma unroll
        for (int r = 0; r < 4; r++) {
            float M = m[a][r];
            #pragma unroll
            for (int off = 1; off < 16; off <<= 1)
                M = fmaxf(M, __shfl_xor(M, off));
            float sc = __expf(m[a][r] - M);
            float L = l[a][r] * sc, S = s[a][r] * sc;
            #pragma unroll
            for (int off = 1; off < 16; off <<= 1) {
                L += __shfl_xor(L, off);
                S += __shfl_xor(S, off);
            }
            if (lo == 0) {
                int row = rbase + a * 16 + hi * 4 + r;
                int idx = chunk * N + row;
                pm[idx] = M; pl[idx] = L; ps[idx] = S;
            }
        }
}

// Merge per-chunk (m,l,s) partials per row; accumulate sum of s/l and the
// positive count. 64 atomics total.
__global__ void merge_kernel(const float* __restrict__ pm, const float* __restrict__ pl,
                             const float* __restrict__ ps, const uint32* __restrict__ rowpos,
                             float* __restrict__ s_acc, uint32* __restrict__ pos_acc) {
    const int row = blockIdx.x * 256 + threadIdx.x;
    float M = -1e30f;
    #pragma unroll
    for (int k = 0; k < NCHUNK; k++) M = fmaxf(M, pm[k * N + row]);
    float L = 0.f, S = 0.f;
    #pragma unroll
    for (int k = 0; k < NCHUNK; k++) {
        float e = __expf(pm[k * N + row] - M);
        L += pl[k * N + row] * e;
        S += ps[k * N + row] * e;
    }
    float r = S / L;
    uint32 pc = rowpos[row];
    #pragma unroll
    for (int off = 32; off > 0; off >>= 1) {
        r  += __shfl_xor(r, off);
        pc += __shfl_xor(pc, off);
    }
    __shared__ float red[4];
    __shared__ uint32 redp[4];
    int lane = threadIdx.x & 63, w = threadIdx.x >> 6;
    if (lane == 0) { red[w] = r; redp[w] = pc; }
    __syncthreads();
    if (threadIdx.x == 0) {
        atomicAdd(s_acc, red[0] + red[1] + red[2] + red[3]);
        atomicAdd(pos_acc, redp[0] + redp[1] + redp[2] + redp[3]);
    }
}

__global__ void final_kernel(const float* __restrict__ s_acc, const uint32* __restrict__ pos_acc,
                             float* __restrict__ out) {
    double S = (double)s_acc[0];
    double C = (double)N * (double)N - (double)pos_acc[0];  // count(simi != 1)
    double n = (double)N;
    out[0] = (float)((2.0 * S + C - n) / (n * n));
}

extern "C" void kernel_launch(void* const* d_in, const int* in_sizes, int n_in,
                              void* d_out, int out_size, void* d_ws, size_t ws_size,
                              hipStream_t stream) {
    const float* f1   = (const float*)d_in[0];
    const float* f2   = (const float*)d_in[1];
    const int*   simi = (const int*)d_in[2];
    float* out = (float*)d_out;
    char* ws = (char*)d_ws;

    float*  acc_s  = (float*)(ws + OFF_ACC);
    uint32* acc_p  = (uint32*)(ws + OFF_ACC + 4);
    float*  sq2    = (float*)(ws + OFF_SQ2);
    uint32* rowpos = (uint32*)(ws + OFF_RPOS);
    float*  pm     = (float*)(ws + OFF_M);
    float*  pl     = (float*)(ws + OFF_L);
    float*  ps     = (float*)(ws + OFF_S);
    unsigned short* f1b = (unsigned short*)(ws + OFF_F1);
    unsigned short* f2b = (unsigned short*)(ws + OFF_F2);
    uint64* packed = (uint64*)(ws + OFF_PACK);

    hipMemsetAsync(ws + OFF_ACC, 0, 64, stream);
    prep_kernel<<<256, 256, 0, stream>>>(f1, f2, f1b, f2b, sq2);
    pack_kernel<<<N / 4, 256, 0, stream>>>(simi, packed, rowpos);
    main_kernel<<<dim3(N / RT, NCHUNK), 256, 0, stream>>>(f1b, f2b, sq2,
                                                          (const uint32*)packed, pm, pl, ps);
    merge_kernel<<<N / 256, 256, 0, stream>>>(pm, pl, ps, rowpos, acc_s, acc_p);
    final_kernel<<<1, 1, 0, stream>>>(acc_s, acc_p, out);
}

// Round 9
// 405.866 us; speedup vs baseline: 1.1102x; 1.0367x over previous
//
#include <hip/hip_runtime.h>
#include <hip/hip_bf16.h>
#include <stdint.h>

#define N 8192
#define D 128
#define NCHUNK 16
#define CHUNK (N / NCHUNK)      // 512 cols per chunk
#define RT 128                  // rows per block (4 waves x 32)
#define CT 64                   // cols per LDS tile
#define NTILES (CHUNK / CT)     // 8
#define NBLK (N / RT * NCHUNK)  // 1024 main blocks

typedef short bf16x8 __attribute__((ext_vector_type(8)));
typedef float f32x4 __attribute__((ext_vector_type(4)));
typedef unsigned int uint32;

// ---- workspace layout (bytes) ----
#define OFF_ACC   0u                          // [0] float S_sum, [4] uint32 C_count
#define OFF_SQ2   1024u                       // 8192 floats
#define OFF_BCNT  (OFF_SQ2 + N * 4u)         // NBLK uint32 per-block negative counts
#define OFF_M     (OFF_BCNT + NBLK * 4u)      // NCHUNK*N floats (per-chunk row max)
#define OFF_L     (OFF_M + NCHUNK * N * 4u)
#define OFF_S     (OFF_L + NCHUNK * N * 4u)
#define OFF_F1    (OFF_S + NCHUNK * N * 4u)   // feat1 bf16
#define OFF_F2    (OFF_F1 + N * D * 2u)       // feat2 bf16

// Convert feats to bf16; compute sq2[j] = ||feat2_j||^2.
__global__ __launch_bounds__(256)
void prep_kernel(const float* __restrict__ f1, const float* __restrict__ f2,
                 unsigned short* __restrict__ f1b, unsigned short* __restrict__ f2b,
                 float* __restrict__ sq2) {
    const int w    = blockIdx.x * 4 + (threadIdx.x >> 6);  // 0..1023
    const int lane = threadIdx.x & 63;
    for (int row = w; row < N; row += 1024) {
        float a0 = f1[row * D + lane];
        float a1 = f1[row * D + 64 + lane];
        float b0 = f2[row * D + lane];
        float b1 = f2[row * D + 64 + lane];
        __hip_bfloat16 t;
        t = __float2bfloat16(a0); f1b[row * D + lane]      = *(unsigned short*)&t;
        t = __float2bfloat16(a1); f1b[row * D + 64 + lane] = *(unsigned short*)&t;
        t = __float2bfloat16(b0); f2b[row * D + lane]      = *(unsigned short*)&t;
        t = __float2bfloat16(b1); f2b[row * D + 64 + lane] = *(unsigned short*)&t;
        float ss = b0 * b0 + b1 * b1;
        #pragma unroll
        for (int off = 32; off > 0; off >>= 1) ss += __shfl_xor(ss, off);
        if (lane == 0) sq2[row] = ss;
    }
}

// FUSED: GEMM + online softmax + raw-simi masking + negative count.
// (pack_kernel deleted — simi is consumed exactly once, here; its loads are
// issued before each tile's staging barrier and consumed after the MFMAs, so
// the barrier's vmcnt(0) drain doubles as the simi BW consumption window.)
// Block = (rowtile, chunk): rows [rowtile*128, +128), cols [chunk*512, +512).
// Wave owns 32 rows (2 A-sets); per-lane online softmax (R7/R8, proven);
// column permutation c(q)=4*(q&15)+(q>>4) makes lane lo's 4 cols contiguous
// -> one int4 simi load per row per tile. Grid = 1024 blocks = 4/CU resident.
__global__ __launch_bounds__(256)
void main_kernel(const unsigned short* __restrict__ f1b,
                 const unsigned short* __restrict__ f2b,
                 const float* __restrict__ sq2,
                 const int* __restrict__ simi,
                 float* __restrict__ pm, float* __restrict__ pl, float* __restrict__ ps,
                 uint32* __restrict__ blockcnt) {
    __shared__ unsigned short ldsB[CT * D];  // 16 KB, XOR-swizzled
    __shared__ uint32 cred[4];

    const int tid  = threadIdx.x;
    const int wave = tid >> 6;
    const int lane = tid & 63;
    const int lo   = lane & 15;
    const int hi   = lane >> 4;

    const int rowtile = blockIdx.x;       // 0..63
    const int chunk   = blockIdx.y;       // 0..15
    const int rbase   = rowtile * RT + wave * 32;
    const int cbase0  = chunk * CHUNK;

    // A fragments: 2 sets of 16 rows, full K=128, resident for the sweep.
    bf16x8 afrag[2][4];
    #pragma unroll
    for (int a = 0; a < 2; a++) {
        const unsigned short* ap = f1b + (size_t)(rbase + a * 16 + lo) * D + hi * 8;
        #pragma unroll
        for (int kk = 0; kk < 4; kk++)
            afrag[a][kk] = *reinterpret_cast<const bf16x8*>(ap + kk * 32);
    }

    const int sq_ = (tid >> 4);           // staging: position within 16-group
    const int sg_ = tid & 15;             // staging: 16B chunk index

    // simi pointer: rows rbase+hi*4 (+a*16+r), cols cbase0 + 4*lo
    const int* simi_p = simi + (size_t)(rbase + hi * 4) * N + cbase0 + 4 * lo;

    // per-lane online-softmax state; negative count
    float m[2][4], l[2][4], s[2][4];
    #pragma unroll
    for (int a = 0; a < 2; a++)
        #pragma unroll
        for (int r = 0; r < 4; r++) { m[a][r] = -1e30f; l[a][r] = 0.f; s[a][r] = 0.f; }
    uint32 cnt = 0;

    for (int t = 0; t < NTILES; t++) {
        const int cbase = cbase0 + t * CT;

        // raw mask loads FIRST (16B each, 4-seg/instr) — in flight through
        // staging + barrier; consumed (converted) right after the barrier.
        int4 mkv[2][4];
        #pragma unroll
        for (int a = 0; a < 2; a++)
            #pragma unroll
            for (int r = 0; r < 4; r++)
                mkv[a][r] = *reinterpret_cast<const int4*>(simi_p + (size_t)(a * 16 + r) * N);

        __syncthreads();  // previous tile's LDS reads complete
        // stage B tile: position q holds global col c(q)=4*(q&15)+(q>>4)
        #pragma unroll
        for (int it = 0; it < 4; it++) {
            int q = it * 16 + sq_;
            int c = 4 * (q & 15) + (q >> 4);
            const uint4 v = *reinterpret_cast<const uint4*>(f2b + (size_t)(cbase + c) * D + sg_ * 8);
            *reinterpret_cast<uint4*>(ldsB + q * D + ((sg_ ^ (q & 15)) * 8)) = v;
        }
        __syncthreads();  // vmcnt(0) here: masks also drained -> convert is free

        // convert raw masks to nibbles + count negatives (frees 24 VGPRs)
        uint32 mb[2][4];
        #pragma unroll
        for (int a = 0; a < 2; a++)
            #pragma unroll
            for (int r = 0; r < 4; r++) {
                int4 v = mkv[a][r];
                uint32 nib = (uint32)(v.x == 1) | ((uint32)(v.y == 1) << 1) |
                             ((uint32)(v.z == 1) << 2) | ((uint32)(v.w == 1) << 3);
                mb[a][r] = nib;
                cnt += 4u - __popc(nib);
            }

        // MFMA: 32 rows x 64 cols; each B fragment feeds both A sets
        f32x4 acc[2][4];
        #pragma unroll
        for (int cf = 0; cf < 4; cf++) {
            acc[0][cf] = (f32x4){0.f, 0.f, 0.f, 0.f};
            acc[1][cf] = (f32x4){0.f, 0.f, 0.f, 0.f};
            const int brow = cf * 16 + lo;
            #pragma unroll
            for (int kk = 0; kk < 4; kk++) {
                int g = kk * 4 + hi;
                bf16x8 b = *reinterpret_cast<const bf16x8*>(
                    ldsB + brow * D + ((g ^ (brow & 15)) * 8));
                acc[0][cf] = __builtin_amdgcn_mfma_f32_16x16x32_bf16(afrag[0][kk], b, acc[0][cf], 0, 0, 0);
                acc[1][cf] = __builtin_amdgcn_mfma_f32_16x16x32_bf16(afrag[1][kk], b, acc[1][cf], 0, 0, 0);
            }
        }

        // logits lg = 2c - sq2[col] (row-constant sq1 dropped); per-lane
        // online max + rescale + accumulate — no cross-lane ops in the loop
        f32x4 sqv = *reinterpret_cast<const f32x4*>(sq2 + cbase0 + t * CT + 4 * lo);
        #pragma unroll
        for (int a = 0; a < 2; a++)
            #pragma unroll
            for (int r = 0; r < 4; r++) {
                float lg[4];
                #pragma unroll
                for (int cf = 0; cf < 4; cf++)
                    lg[cf] = 2.0f * acc[a][cf][r] - sqv[cf];
                float tm = fmaxf(fmaxf(lg[0], lg[1]), fmaxf(lg[2], lg[3]));
                float mn = fmaxf(m[a][r], tm);
                float al = __expf(m[a][r] - mn);
                m[a][r] = mn;
                float p[4];
                #pragma unroll
                for (int cf = 0; cf < 4; cf++) p[cf] = __expf(lg[cf] - mn);
                l[a][r] = l[a][r] * al + ((p[0] + p[1]) + (p[2] + p[3]));
                float sm = 0.f;
                #pragma unroll
                for (int cf = 0; cf < 4; cf++)
                    sm += ((mb[a][r] >> cf) & 1u) ? p[cf] : 0.f;
                s[a][r] = s[a][r] * al + sm;
            }
        simi_p += CT;
    }

    // end: cross-lane (lo group, 16 lanes) max + rescale + sum, once
    #pragma unroll
    for (int a = 0; a < 2; a++)
        #pragma unroll
        for (int r = 0; r < 4; r++) {
            float M = m[a][r];
            #pragma unroll
            for (int off = 1; off < 16; off <<= 1)
                M = fmaxf(M, __shfl_xor(M, off));
            float sc = __expf(m[a][r] - M);
            float L = l[a][r] * sc, S = s[a][r] * sc;
            #pragma unroll
            for (int off = 1; off < 16; off <<= 1) {
                L += __shfl_xor(L, off);
                S += __shfl_xor(S, off);
            }
            if (lo == 0) {
                int row = rbase + a * 16 + hi * 4 + r;
                int idx = chunk * N + row;
                pm[idx] = M; pl[idx] = L; ps[idx] = S;
            }
        }

    // negative count: wave reduce -> LDS -> one plain store per block
    #pragma unroll
    for (int off = 1; off < 64; off <<= 1) cnt += __shfl_xor(cnt, off);
    if (lane == 0) cred[wave] = cnt;
    __syncthreads();
    if (tid == 0)
        blockcnt[blockIdx.y * 64 + blockIdx.x] = cred[0] + cred[1] + cred[2] + cred[3];
}

// Merge per-chunk (m,l,s) partials per row; accumulate sum of s/l and the
// negative count (from 1024 per-block partials). 64 atomics total.
__global__ void merge_kernel(const float* __restrict__ pm, const float* __restrict__ pl,
                             const float* __restrict__ ps, const uint32* __restrict__ blockcnt,
                             float* __restrict__ s_acc, uint32* __restrict__ neg_acc) {
    const int row = blockIdx.x * 256 + threadIdx.x;
    float M = -1e30f;
    #pragma unroll
    for (int k = 0; k < NCHUNK; k++) M = fmaxf(M, pm[k * N + row]);
    float L = 0.f, S = 0.f;
    #pragma unroll
    for (int k = 0; k < NCHUNK; k++) {
        float e = __expf(pm[k * N + row] - M);
        L += pl[k * N + row] * e;
        S += ps[k * N + row] * e;
    }
    float r = S / L;
    uint32 pc = (threadIdx.x < 32) ? blockcnt[blockIdx.x * 32 + threadIdx.x] : 0u;
    #pragma unroll
    for (int off = 32; off > 0; off >>= 1) {
        r  += __shfl_xor(r, off);
        pc += __shfl_xor(pc, off);
    }
    __shared__ float red[4];
    __shared__ uint32 redp[4];
    int lane = threadIdx.x & 63, w = threadIdx.x >> 6;
    if (lane == 0) { red[w] = r; redp[w] = pc; }
    __syncthreads();
    if (threadIdx.x == 0) {
        atomicAdd(s_acc, red[0] + red[1] + red[2] + red[3]);
        atomicAdd(neg_acc, redp[0] + redp[1] + redp[2] + redp[3]);
    }
}

__global__ void final_kernel(const float* __restrict__ s_acc, const uint32* __restrict__ neg_acc,
                             float* __restrict__ out) {
    double S = (double)s_acc[0];
    double C = (double)neg_acc[0];   // count(simi != 1), counted directly
    double n = (double)N;
    out[0] = (float)((2.0 * S + C - n) / (n * n));
}

extern "C" void kernel_launch(void* const* d_in, const int* in_sizes, int n_in,
                              void* d_out, int out_size, void* d_ws, size_t ws_size,
                              hipStream_t stream) {
    const float* f1   = (const float*)d_in[0];
    const float* f2   = (const float*)d_in[1];
    const int*   simi = (const int*)d_in[2];
    float* out = (float*)d_out;
    char* ws = (char*)d_ws;

    float*  acc_s    = (float*)(ws + OFF_ACC);
    uint32* acc_n    = (uint32*)(ws + OFF_ACC + 4);
    float*  sq2      = (float*)(ws + OFF_SQ2);
    uint32* blockcnt = (uint32*)(ws + OFF_BCNT);
    float*  pm       = (float*)(ws + OFF_M);
    float*  pl       = (float*)(ws + OFF_L);
    float*  ps       = (float*)(ws + OFF_S);
    unsigned short* f1b = (unsigned short*)(ws + OFF_F1);
    unsigned short* f2b = (unsigned short*)(ws + OFF_F2);

    hipMemsetAsync(ws + OFF_ACC, 0, 64, stream);
    prep_kernel<<<256, 256, 0, stream>>>(f1, f2, f1b, f2b, sq2);
    main_kernel<<<dim3(N / RT, NCHUNK), 256, 0, stream>>>(f1b, f2b, sq2, simi,
                                                          pm, pl, ps, blockcnt);
    merge_kernel<<<N / 256, 256, 0, stream>>>(pm, pl, ps, blockcnt, acc_s, acc_n);
    final_kernel<<<1, 1, 0, stream>>>(acc_s, acc_n, out);
}